// Round 10
// baseline (676.967 us; speedup 1.0000x reference)
//
#include <hip/hip_runtime.h>
#include <hip/hip_bf16.h>
#include <stdint.h>

typedef __hip_bfloat16 bf16;
typedef __attribute__((ext_vector_type(8))) short frag8;     // 8 bf16 = 4 VGPRs
typedef __attribute__((ext_vector_type(4))) float floatx4;   // MFMA acc

#define B_WIN 512
#define L_TOK 196
#define C_DIM 384
#define NH    12
#define HD    32
#define QP    208   // 13*16 q-rows padded
#define KPAD  224   // 14*16 k padded (exactly 56 P-vals/lane = 7 PV chunks)
#define VSTR  236   // vT row stride: 472B. write: 2-way; read: free
#define GK    384   // gemm K (both gemms)
#define NST   12    // GK/32 k-steps
// scale = hd^-0.5 * log2(e)  (exp2 softmax; base change folded into logits+bias)
#define QSCALE 0.2550348555f

#if defined(__has_builtin)
#if __has_builtin(__builtin_amdgcn_exp2f)
#define EXP2(x) __builtin_amdgcn_exp2f(x)
#endif
#endif
#ifndef EXP2
#define EXP2(x) exp2f(x)
#endif

__device__ __forceinline__ void async_cp16(const void* g, void* l) {
  __builtin_amdgcn_global_load_lds(
      (const __attribute__((address_space(1))) unsigned int*)g,
      (__attribute__((address_space(3))) unsigned int*)l, 16, 0, 0);
}

__device__ __forceinline__ unsigned short f2bf_bits(float f) {
  bf16 b = __float2bfloat16(f);
  return *(unsigned short*)&b;
}

__device__ __forceinline__ float bfu2f(short u) {
  union { uint32_t i; float f; } c;
  c.i = ((uint32_t)(unsigned short)u) << 16;
  return c.f;
}

// ---------------- x cast: fp32 -> bf16, 4 elems/thread ----------------
__global__ void cast_to_bf16(const float* __restrict__ src, bf16* __restrict__ dst) {
  int i = blockIdx.x * 256 + threadIdx.x;   // grid sized exactly: n/4 threads
  float4 v = ((const float4*)src)[i];
  ushort4 o;
  o.x = f2bf_bits(v.x); o.y = f2bf_bits(v.y);
  o.z = f2bf_bits(v.z); o.w = f2bf_bits(v.w);
  ((ushort4*)dst)[i] = o;
}

// ---------------- weight transpose+cast: src[K][N] fp32 -> dst[N][K] bf16 ----
__global__ void transpose_cast(const float* __restrict__ src, bf16* __restrict__ dst,
                               int K, int N) {
  int idx = blockIdx.x * 256 + threadIdx.x;
  if (idx >= K * N) return;
  int k = idx / N, n = idx - k * N;
  dst[n * K + k] = __float2bfloat16(src[idx]);
}

// ------- bias precompute (bf16, per-kk contiguous): biasb[h][q 208][r2 224] ---
// r2 = kk*32 + quad*8 + i; maps to k = kk*32 + quad*8 + (i>=4?4:0) + (i&3)
// (the pi-permuted position matching the swapped-QK register layout, so each
//  lane reads ONE bf16x8 per kk). Pre-multiplied by log2(e).
// k >= 196: -1e30 (exp2 -> 0 masks those columns; K pad rows need no zeroing).
__global__ void bias_fill(const float* __restrict__ table, const int* __restrict__ rel,
                          bf16* __restrict__ biasb) {
  int idx = blockIdx.x * 256 + threadIdx.x;  // 12*208*224 = 559104 exact
  int h = idx / (QP * KPAD);
  int rem = idx - h * (QP * KPAD);
  int q = rem / KPAD, r2 = rem - q * KPAD;
  int kk = r2 >> 5, quad = (r2 >> 3) & 3, i = r2 & 7;
  int k = kk * 32 + quad * 8 + ((i >= 4) ? 4 : 0) + (i & 3);
  float v;
  if (q >= L_TOK)      v = 0.f;
  else if (k >= L_TOK) v = -1e30f;
  else                 v = table[rel[q * L_TOK + k] * NH + h] * 1.4426950408889634f;
  biasb[idx] = __float2bfloat16(v);
}

__device__ __forceinline__ void storev(bf16* p, float v)  { *p = __float2bfloat16(v); }
__device__ __forceinline__ void storev(float* p, float v) { *p = v; }

// ------- GEMM: C[M,N] = A[M,K=384](LDA) @ Bt[N,384]^T + bias ------------------
// v3 structure (r9 post-mortem: operand roles were BACKWARDS):
//  - A (STREAMING, HBM-served: x / attn-out, 77 MB) -> async LDS staging,
//    3-buffer, 2-ahead, counted vmcnt. The async pipeline hides ~900cy HBM.
//  - B (L2-HOT: wT1 0.88 MB / wT2 0.29 MB, shared by ALL 784 bm-blocks) ->
//    DIRECT per-lane frag8 loads, 1-step register prefetch. ~200cy L2-hit
//    latency is covered by one iteration (~300cy).
// LDS traffic/step = 8 KB write + 16 KB read = 24 KB (192cy) < MFMA 256cy.
// vmcnt derivation: prologue [A0:2, B0:4, A1:2] -> vmcnt(2) = A0+B0 landed.
// Steady state per iter: issue B_{t+1}(4), A_{t+2}(2); compiler inserts
// vmcnt(8) before MFMA (drains B_t); manual vmcnt(6) drains A_{t+1} for the
// next iter. Never 0 in the loop. Tail: clamped dup loads into the dead
// buffer (not read after the last barrier -> no race).
template <typename OT, int LDA>
__global__ __launch_bounds__(256) void gemm_bt(
    const bf16* __restrict__ A, const bf16* __restrict__ Bt,
    const float* __restrict__ bias, OT* __restrict__ C,
    int M, int N, int qcols, int nbn, int panel) {
  __shared__ __align__(16) bf16 sA[3][128 * 32];   // 24576 B
  const int tid = threadIdx.x;
  const int wave = tid >> 6, lane = tid & 63;
  const int SUPER = panel * nbn;
  const int bid = blockIdx.x;
  const int sb = bid / SUPER, rsp = bid - sb * SUPER;
  const long bm = (long)(sb * panel + rsp % panel) * 128;
  const long bn = (long)(rsp / panel) * 128;

  const int colb = lane & 15;
  const int quad = lane >> 4;
  const int srow = wave * 32 + (lane >> 2);
  const int scol = (lane & 3) * 8;
  const bf16* gA = A + (bm + srow) * (long)LDA + scol;   // LDS staging source

  const int wr = (wave & 1) * 64;
  const int wc = (wave >> 1) * 64;
  // B frag base: row = bn + wc + ni*16 + colb, k = s*32 + quad*8 (+i)
  const bf16* gBf = Bt + (bn + wc + colb) * (long)GK + quad * 8;

  floatx4 acc[4][4];
#pragma unroll
  for (int i = 0; i < 4; i++)
#pragma unroll
    for (int j = 0; j < 4; j++) acc[i][j] = (floatx4)(0.f);

#define STAGEA(s, buf)                                                       \
  do {                                                                       \
    _Pragma("unroll")                                                        \
    for (int j = 0; j < 2; j++)                                              \
      async_cp16(gA + (size_t)j * 16 * LDA + (s) * 32,                       \
                 &sA[buf][(wave * 32 + j * 16) * 32]);                       \
  } while (0)
#define LOADB(dst, s)                                                        \
  do {                                                                       \
    _Pragma("unroll")                                                        \
    for (int ni = 0; ni < 4; ni++)                                           \
      dst[ni] = *(const frag8*)(gBf + (size_t)ni * 16 * GK + (s) * 32);      \
  } while (0)

  frag8 bfc[4], bfn[4];
  // prologue (fences pin vmem issue order: [A0:2, B0:4, A1:2])
  STAGEA(0, 0);
  asm volatile("" ::: "memory");
  LOADB(bfc, 0);
  asm volatile("" ::: "memory");
  STAGEA(1, 1);
  asm volatile("s_waitcnt vmcnt(2)" ::: "memory");   // A0 + B0 landed, A1 flying
  __builtin_amdgcn_s_barrier();

  int cur = 0;
#pragma unroll
  for (int t = 0; t < NST; ++t) {
    const int sb2 = (t + 1 < NST) ? t + 1 : NST - 1; // clamped dup load at tail
    LOADB(bfn, sb2);
    const int sa2 = (t + 2 < NST) ? t + 2 : NST - 1; // restage into dead buf
    int nb = cur + 2; if (nb >= 3) nb -= 3;
    STAGEA(sa2, nb);

    frag8 afr[4];
#pragma unroll
    for (int mi = 0; mi < 4; mi++)
      afr[mi] = *(const frag8*)&sA[cur][(wr + mi * 16 + colb) * 32 + quad * 8];
#pragma unroll
    for (int mi = 0; mi < 4; mi++)
#pragma unroll
      for (int ni = 0; ni < 4; ni++)
        acc[mi][ni] = __builtin_amdgcn_mfma_f32_16x16x32_bf16(afr[mi], bfc[ni], acc[mi][ni], 0, 0, 0);
#pragma unroll
    for (int ni = 0; ni < 4; ni++) bfc[ni] = bfn[ni];

    if (t + 1 < NST) {
      // drains only the 2 OLDEST vmem ops = A_{t+1}'s stage (needed next iter)
      asm volatile("s_waitcnt vmcnt(6)" ::: "memory");
      __builtin_amdgcn_s_barrier();
    }
    cur = (cur == 2) ? 0 : cur + 1;
  }
#undef STAGEA
#undef LOADB

#pragma unroll
  for (int ni = 0; ni < 4; ni++) {
    const long col = bn + wc + ni * 16 + colb;
    const float bv = bias[col];
#pragma unroll
    for (int mi = 0; mi < 4; mi++)
#pragma unroll
      for (int r = 0; r < 4; r++) {
        const long row = bm + wr + mi * 16 + quad * 4 + r;
        float val = acc[mi][ni][r] + bv;
        if (col < qcols) val *= QSCALE;
        storev(&C[row * N + col], val);
      }
  }
}

// ---------------- fused window attention (v7: v5/v6 hybrid, no forced cap) ---
// 256 threads / 4 waves, NO min-waves clause (r2/r4 lesson: forcing spills).
// Register diet instead: QK/PV interleaved per kk (transient ap, 4 VGPR),
// bf16 bias one frag8 per kk, Q loaded JIT per rg.
__global__ __launch_bounds__(256) void attn_win(
    bf16* __restrict__ qkv, const bf16* __restrict__ biasb) {
  __shared__ __align__(16) bf16 kL[KPAD * 32];     // 14336 B, linear 64B rows
  __shared__ __align__(16) bf16 vT[HD * VSTR];     // 15104 B  (total 29440 B)
  const int b = blockIdx.x, h = blockIdx.y;
  const int tid = threadIdx.x, wave = tid >> 6, lane = tid & 63;
  bf16* base = qkv + (size_t)b * L_TOK * (3 * C_DIM);

  const int colb = lane & 15;
  const int quad = lane >> 4;
  const int rsub = quad * 4;
  const int kswz = (quad ^ ((colb >> 1) & 3)) * 8;   // slot-XOR for kL reads

  // ---- V gather: issue ALL global loads first (oldest in vmem queue) ----
  const bf16* vbase = base + 2 * C_DIM + h * HD;
  const int r0a = tid >> 2, c8a = (tid & 3) * 8;
  const bf16* ga = vbase + (size_t)(2 * r0a) * (3 * C_DIM) + c8a;
  uint4 a0 = *(const uint4*)ga;
  uint4 a1 = *(const uint4*)(ga + 3 * C_DIM);
  const int i1 = tid + 256;
  const bool h1 = i1 < 392;
  const int r0b = h1 ? (i1 >> 2) : r0a, c8b = h1 ? (i1 & 3) * 8 : c8a;
  const bf16* gb = vbase + (size_t)(2 * r0b) * (3 * C_DIM) + c8b;
  uint4 b0 = make_uint4(0, 0, 0, 0), b1 = make_uint4(0, 0, 0, 0);
  if (h1) { b0 = *(const uint4*)gb; b1 = *(const uint4*)(gb + 3 * C_DIM); }

  // ---- K: async global->LDS, 14 chunks of 1024B (rows j = c*16..c*16+15).
  // LDS is linear; the slot permutation is applied on the global source:
  // LDS slot w of row j holds K[pi(j)] quad (w ^ ((j>>1)&3)).
  for (int c = wave; c < 14; c += 4) {
    const int j = c * 16 + (lane >> 2);
    const int slot = lane & 3;
    const int t = j >> 4, qd = (j >> 2) & 3, rr = j & 3;
    int k = (t >> 1) * 32 + qd * 8 + (t & 1) * 4 + rr;
    if (k > L_TOK - 1) k = L_TOK - 1;       // clamp: bias -1e30 masks these cols
    const int sj = (j >> 1) & 3;
    const bf16* src = base + (size_t)k * (3 * C_DIM) + C_DIM + h * HD + ((slot ^ sj) * 8);
    async_cp16(src, &kL[c * 512]);
  }

  // ---- V transpose writes (vmcnt wait covers only the V loads) ----
  {
    ushort ea0[8], ea1[8];
    *(uint4*)ea0 = a0; *(uint4*)ea1 = a1;
#pragma unroll
    for (int e = 0; e < 8; e++) {
      uint32_t pack = (uint32_t)ea0[e] | ((uint32_t)ea1[e] << 16);
      *(uint32_t*)&vT[(c8a + e) * VSTR + 2 * r0a] = pack;
    }
    if (h1) {
      ushort eb0[8], eb1[8];
      *(uint4*)eb0 = b0; *(uint4*)eb1 = b1;
#pragma unroll
      for (int e = 0; e < 8; e++) {
        uint32_t pack = (uint32_t)eb0[e] | ((uint32_t)eb1[e] << 16);
        *(uint32_t*)&vT[(c8b + e) * VSTR + 2 * r0b] = pack;
      }
    }
  }
  // zero V pad rows [196,224) (P there is exactly 0, but LDS garbage could be NaN)
  for (int idx = tid; idx < HD * 14; idx += 256) {
    int d = idx / 14, pr = idx - d * 14;
    *(uint32_t*)&vT[d * VSTR + L_TOK + 2 * pr] = 0;
  }
  __syncthreads();

  const bf16* biasB = biasb + (size_t)h * QP * KPAD;

#pragma unroll
  for (int ii = 0; ii < 4; ii++) {
    const int rg = wave + 4 * ii;
    if (rg < 13) {
      const int row0 = rg * 16;
      int qrow = row0 + colb; if (qrow > L_TOK - 1) qrow = L_TOK - 1;
      const frag8 aq = *(const frag8*)(base + (size_t)qrow * (3 * C_DIM) + h * HD + quad * 8);
      const bf16* bRow = biasB + (size_t)(row0 + colb) * KPAD;

      floatx4 o0 = (floatx4)(0.f), o1 = (floatx4)(0.f);
      float lsum = 0.f;
#pragma unroll
      for (int kk = 0; kk < 7; kk++) {
        const frag8 k0 = *(const frag8*)&kL[((2 * kk) * 16 + colb) * 32 + kswz];
        const frag8 k1 = *(const frag8*)&kL[((2 * kk + 1) * 16 + colb) * 32 + kswz];
        floatx4 s0 = __builtin_amdgcn_mfma_f32_16x16x32_bf16(k0, aq, (floatx4)(0.f), 0, 0, 0);
        floatx4 s1 = __builtin_amdgcn_mfma_f32_16x16x32_bf16(k1, aq, (floatx4)(0.f), 0, 0, 0);
        const frag8 bb = *(const frag8*)&bRow[kk * 32 + quad * 8];
        frag8 ap;
#pragma unroll
        for (int e = 0; e < 4; e++) {
          float p = EXP2(s0[e] + bfu2f(bb[e]));
          lsum += p;
          ap[e] = (short)f2bf_bits(p);
        }
#pragma unroll
        for (int e = 0; e < 4; e++) {
          float p = EXP2(s1[e] + bfu2f(bb[4 + e]));
          lsum += p;
          ap[4 + e] = (short)f2bf_bits(p);
        }
        const frag8 bv0 = *(const frag8*)&vT[colb * VSTR + kk * 32 + quad * 8];
        const frag8 bv1 = *(const frag8*)&vT[(16 + colb) * VSTR + kk * 32 + quad * 8];
        o0 = __builtin_amdgcn_mfma_f32_16x16x32_bf16(ap, bv0, o0, 0, 0, 0);
        o1 = __builtin_amdgcn_mfma_f32_16x16x32_bf16(ap, bv1, o1, 0, 0, 0);
      }
      lsum += __shfl_xor(lsum, 16, 64);
      lsum += __shfl_xor(lsum, 32, 64);
      const float rl = 1.0f / lsum;
#pragma unroll
      for (int r = 0; r < 4; r++) {
        const float rn = __shfl(rl, rsub + r, 64);
        const int grow = row0 + rsub + r;
        if (grow < L_TOK) {
          base[(size_t)grow * (3 * C_DIM) + h * HD + colb] = __float2bfloat16(o0[r] * rn);
          base[(size_t)grow * (3 * C_DIM) + h * HD + 16 + colb] = __float2bfloat16(o1[r] * rn);
        }
      }
    }
  }
}

extern "C" void kernel_launch(void* const* d_in, const int* in_sizes, int n_in,
                              void* d_out, int out_size, void* d_ws, size_t ws_size,
                              hipStream_t stream) {
  const float* x      = (const float*)d_in[0];
  const float* qkv_w  = (const float*)d_in[1];
  const float* qkv_b  = (const float*)d_in[2];
  const float* proj_w = (const float*)d_in[3];
  const float* proj_b = (const float*)d_in[4];
  const float* btab   = (const float*)d_in[5];
  const int*   relidx = (const int*)d_in[6];
  float* out = (float*)d_out;

  const size_t M = (size_t)B_WIN * L_TOK;  // 100352
  char* ws = (char*)d_ws;
  size_t off = 0;
  bf16*  qkv   = (bf16*)(ws + off);  off += M * 1152 * 2;              // 231.2 MB
  bf16*  wT1   = (bf16*)(ws + off);  off += (size_t)1152 * 384 * 2;    // 0.88 MB
  bf16*  wT2   = (bf16*)(ws + off);  off += (size_t)384 * 384 * 2;     // 0.29 MB
  bf16*  biasb = (bf16*)(ws + off);  off += (size_t)NH * QP * KPAD * 2;// 1.12 MB

  // x cast to bf16: prefer workspace; fall back to d_out aliasing.
  bf16* xb = (ws_size >= off + M * C_DIM * sizeof(bf16))
                 ? (bf16*)(ws + off) : (bf16*)d_out;

  cast_to_bf16<<<(int)(M * C_DIM / 4 / 256), 256, 0, stream>>>(x, xb);
  transpose_cast<<<(384 * 1152 + 255) / 256, 256, 0, stream>>>(qkv_w, wT1, 384, 1152);
  transpose_cast<<<(384 * 384 + 255) / 256, 256, 0, stream>>>(proj_w, wT2, 384, 384);
  bias_fill<<<(NH * QP * KPAD) / 256, 256, 0, stream>>>(btab, relidx, biasb);

  gemm_bt<bf16, 384><<<784 * 9, 256, 0, stream>>>(xb, wT1, qkv_b, qkv,
                                                  (int)M, 1152, C_DIM, 9, 28);
  attn_win<<<dim3(B_WIN, NH), 256, 0, stream>>>(qkv, biasb);
  gemm_bt<float, 1152><<<784 * 3, 256, 0, stream>>>(qkv, wT2, proj_b, out,
                                                    (int)M, 384, 0, 3, 28);
}

// Round 12
// 629.016 us; speedup vs baseline: 1.0762x; 1.0762x over previous
//
#include <hip/hip_runtime.h>
#include <hip/hip_bf16.h>
#include <stdint.h>

typedef __hip_bfloat16 bf16;
typedef __attribute__((ext_vector_type(8))) short frag8;     // 8 bf16 = 4 VGPRs
typedef __attribute__((ext_vector_type(4))) float floatx4;   // MFMA acc

#define B_WIN 512
#define L_TOK 196
#define C_DIM 384
#define NH    12
#define HD    32
#define QP    208   // 13*16 q-rows padded
#define KPAD  224   // 14*16 k padded (exactly 56 P-vals/lane = 7 PV chunks)
#define VSTR  236   // vT row stride: 472B. write: 2-way; read: free
#define GK    384   // gemm K (both gemms)
#define NST   12    // GK/32 k-steps
// scale = hd^-0.5 * log2(e)  (exp2 softmax; base change folded into logits+bias)
#define QSCALE 0.2550348555f

#if defined(__has_builtin)
#if __has_builtin(__builtin_amdgcn_exp2f)
#define EXP2(x) __builtin_amdgcn_exp2f(x)
#endif
#endif
#ifndef EXP2
#define EXP2(x) exp2f(x)
#endif

__device__ __forceinline__ void async_cp16(const void* g, void* l) {
  __builtin_amdgcn_global_load_lds(
      (const __attribute__((address_space(1))) unsigned int*)g,
      (__attribute__((address_space(3))) unsigned int*)l, 16, 0, 0);
}

__device__ __forceinline__ unsigned short f2bf_bits(float f) {
  bf16 b = __float2bfloat16(f);
  return *(unsigned short*)&b;
}

__device__ __forceinline__ float bfu2f(short u) {
  union { uint32_t i; float f; } c;
  c.i = ((uint32_t)(unsigned short)u) << 16;
  return c.f;
}

// ---------------- x cast: fp32 -> bf16, 4 elems/thread ----------------
__global__ void cast_to_bf16(const float* __restrict__ src, bf16* __restrict__ dst) {
  int i = blockIdx.x * 256 + threadIdx.x;   // grid sized exactly: n/4 threads
  float4 v = ((const float4*)src)[i];
  ushort4 o;
  o.x = f2bf_bits(v.x); o.y = f2bf_bits(v.y);
  o.z = f2bf_bits(v.z); o.w = f2bf_bits(v.w);
  ((ushort4*)dst)[i] = o;
}

// ---------------- weight transpose+cast: src[K][N] fp32 -> dst[N][K] bf16 ----
__global__ void transpose_cast(const float* __restrict__ src, bf16* __restrict__ dst,
                               int K, int N) {
  int idx = blockIdx.x * 256 + threadIdx.x;
  if (idx >= K * N) return;
  int k = idx / N, n = idx - k * N;
  dst[n * K + k] = __float2bfloat16(src[idx]);
}

// ------- bias precompute (bf16, per-kk contiguous): biasb[h][q 208][r2 224] ---
// r2 = kk*32 + quad*8 + i; maps to k = kk*32 + quad*8 + (i>=4?4:0) + (i&3)
// (the pi-permuted position matching the swapped-QK register layout, so each
//  lane reads ONE bf16x8 per kk). Pre-multiplied by log2(e).
// k >= 196: -1e30 (exp2 -> 0 masks those columns; K pad rows need no zeroing).
__global__ void bias_fill(const float* __restrict__ table, const int* __restrict__ rel,
                          bf16* __restrict__ biasb) {
  int idx = blockIdx.x * 256 + threadIdx.x;  // 12*208*224 = 559104 exact
  int h = idx / (QP * KPAD);
  int rem = idx - h * (QP * KPAD);
  int q = rem / KPAD, r2 = rem - q * KPAD;
  int kk = r2 >> 5, quad = (r2 >> 3) & 3, i = r2 & 7;
  int k = kk * 32 + quad * 8 + ((i >= 4) ? 4 : 0) + (i & 3);
  float v;
  if (q >= L_TOK)      v = 0.f;
  else if (k >= L_TOK) v = -1e30f;
  else                 v = table[rel[q * L_TOK + k] * NH + h] * 1.4426950408889634f;
  biasb[idx] = __float2bfloat16(v);
}

__device__ __forceinline__ void storev(bf16* p, float v)  { *p = __float2bfloat16(v); }
__device__ __forceinline__ void storev(float* p, float v) { *p = v; }

// ------- GEMM: C[M,N] = A[M,K=384](LDA) @ Bt[N,384]^T + bias ------------------
// v4 (r10 post-mortem): BOTH operands back in the async LDS pipeline (r5's
// verified skeleton -- direct per-lane loads in the MFMA path stall the wave
// in s_waitcnt regardless of which operand, r9/r10 identical at 225us).
// Change vs r5: RETILE 128x128 -> 256x128 block, 4 waves stacked vertically,
// per-wave tile 64x128 (acc[4][8], 32 MFMA/step/wave). Per block-step:
// LDS = 24KB stage + 48KB read = 72KB (562cy) for 128 MFMA (614cy) -> MFMA
// becomes the binding resource (r5: 48KB/375cy vs 64 MFMA/256cy = LDS-bound).
// Same 3-buffer 2-ahead counted-vmcnt sync: stage = 6 ops/wave -> vmcnt(6)
// drains stage t+1 (t+2 stays in flight); never 0 in the loop. Dead-buffer
// rotation race-safe: buf cur+2 was last read in iter t-1 before its barrier.
template <typename OT, int LDA>
__global__ __launch_bounds__(256) void gemm_bt(
    const bf16* __restrict__ A, const bf16* __restrict__ Bt,
    const float* __restrict__ bias, OT* __restrict__ C,
    int M, int N, int qcols, int nbn, int panel) {
  __shared__ __align__(16) bf16 sA[3][256 * 32];   // 3 x 16KB
  __shared__ __align__(16) bf16 sB[3][128 * 32];   // 3 x 8KB  (total 73728 B)
  const int tid = threadIdx.x;
  const int wave = tid >> 6, lane = tid & 63;
  const int SUPER = panel * nbn;
  const int bid = blockIdx.x;
  const int sb = bid / SUPER, rsp = bid - sb * SUPER;
  const long bm = (long)(sb * panel + rsp % panel) * 256;
  const long bn = (long)(rsp / panel) * 128;

  const int colb = lane & 15;
  const int quad = lane >> 4;
  const int srw = lane >> 2;          // staging row within 16-row chunk
  const int scl = (lane & 3) * 8;     // staging 16B slot
  const bf16* gA = A + (bm + wave * 64 + srw) * (long)LDA + scl;
  const bf16* gB = Bt + (bn + wave * 32 + srw) * (long)GK + scl;

  const int wr = wave * 64;           // wave's 64-row slice of the 256-row tile

  floatx4 acc[4][8];
#pragma unroll
  for (int i = 0; i < 4; i++)
#pragma unroll
    for (int j = 0; j < 8; j++) acc[i][j] = (floatx4)(0.f);

#define STAGE(s, buf)                                                        \
  do {                                                                       \
    _Pragma("unroll")                                                        \
    for (int jj = 0; jj < 4; jj++)                                           \
      async_cp16(gA + (size_t)jj * 16 * LDA + (s) * 32,                      \
                 &sA[buf][(wave * 64 + jj * 16) * 32]);                      \
    _Pragma("unroll")                                                        \
    for (int j = 0; j < 2; j++)                                              \
      async_cp16(gB + (size_t)j * 16 * GK + (s) * 32,                        \
                 &sB[buf][(wave * 32 + j * 16) * 32]);                       \
  } while (0)

  STAGE(0, 0);
  STAGE(1, 1);
  asm volatile("s_waitcnt vmcnt(6)" ::: "memory");   // stage 0 landed, 1 flying
  __builtin_amdgcn_s_barrier();

  int cur = 0;
#pragma unroll
  for (int t = 0; t < NST; ++t) {
    const int s2 = (t + 2 < NST) ? t + 2 : NST - 1;  // clamped dup at tail
    int nb = cur + 2; if (nb >= 3) nb -= 3;          // dead buffer
    STAGE(s2, nb);

    frag8 af[4];
#pragma unroll
    for (int mi = 0; mi < 4; mi++)
      af[mi] = *(const frag8*)&sA[cur][(wr + mi * 16 + colb) * 32 + quad * 8];
#pragma unroll
    for (int ni = 0; ni < 8; ni++) {
      const frag8 bfr = *(const frag8*)&sB[cur][(ni * 16 + colb) * 32 + quad * 8];
#pragma unroll
      for (int mi = 0; mi < 4; mi++)
        acc[mi][ni] = __builtin_amdgcn_mfma_f32_16x16x32_bf16(af[mi], bfr, acc[mi][ni], 0, 0, 0);
    }

    if (t + 1 < NST) {
      // outstanding: stage t+1 (6) + stage t+2 (6); drain t+1, keep t+2 flying
      asm volatile("s_waitcnt vmcnt(6)" ::: "memory");
      __builtin_amdgcn_s_barrier();
    }
    cur = (cur == 2) ? 0 : cur + 1;
  }
#undef STAGE

#pragma unroll
  for (int ni = 0; ni < 8; ni++) {
    const long col = bn + ni * 16 + colb;
    const float bv = bias[col];
#pragma unroll
    for (int mi = 0; mi < 4; mi++)
#pragma unroll
      for (int r = 0; r < 4; r++) {
        const long row = bm + wr + mi * 16 + quad * 4 + r;
        float val = acc[mi][ni][r] + bv;
        if (col < qcols) val *= QSCALE;
        storev(&C[row * N + col], val);
      }
  }
}

// ---------------- fused window attention (v7: v5/v6 hybrid, no forced cap) ---
// 256 threads / 4 waves, NO min-waves clause (r2/r4 lesson: forcing spills).
// Register diet instead: QK/PV interleaved per kk (transient ap, 4 VGPR),
// bf16 bias one frag8 per kk, Q loaded JIT per rg.
__global__ __launch_bounds__(256) void attn_win(
    bf16* __restrict__ qkv, const bf16* __restrict__ biasb) {
  __shared__ __align__(16) bf16 kL[KPAD * 32];     // 14336 B, linear 64B rows
  __shared__ __align__(16) bf16 vT[HD * VSTR];     // 15104 B  (total 29440 B)
  const int b = blockIdx.x, h = blockIdx.y;
  const int tid = threadIdx.x, wave = tid >> 6, lane = tid & 63;
  bf16* base = qkv + (size_t)b * L_TOK * (3 * C_DIM);

  const int colb = lane & 15;
  const int quad = lane >> 4;
  const int rsub = quad * 4;
  const int kswz = (quad ^ ((colb >> 1) & 3)) * 8;   // slot-XOR for kL reads

  // ---- V gather: issue ALL global loads first (oldest in vmem queue) ----
  const bf16* vbase = base + 2 * C_DIM + h * HD;
  const int r0a = tid >> 2, c8a = (tid & 3) * 8;
  const bf16* ga = vbase + (size_t)(2 * r0a) * (3 * C_DIM) + c8a;
  uint4 a0 = *(const uint4*)ga;
  uint4 a1 = *(const uint4*)(ga + 3 * C_DIM);
  const int i1 = tid + 256;
  const bool h1 = i1 < 392;
  const int r0b = h1 ? (i1 >> 2) : r0a, c8b = h1 ? (i1 & 3) * 8 : c8a;
  const bf16* gb = vbase + (size_t)(2 * r0b) * (3 * C_DIM) + c8b;
  uint4 b0 = make_uint4(0, 0, 0, 0), b1 = make_uint4(0, 0, 0, 0);
  if (h1) { b0 = *(const uint4*)gb; b1 = *(const uint4*)(gb + 3 * C_DIM); }

  // ---- K: async global->LDS, 14 chunks of 1024B (rows j = c*16..c*16+15).
  // LDS is linear; the slot permutation is applied on the global source:
  // LDS slot w of row j holds K[pi(j)] quad (w ^ ((j>>1)&3)).
  for (int c = wave; c < 14; c += 4) {
    const int j = c * 16 + (lane >> 2);
    const int slot = lane & 3;
    const int t = j >> 4, qd = (j >> 2) & 3, rr = j & 3;
    int k = (t >> 1) * 32 + qd * 8 + (t & 1) * 4 + rr;
    if (k > L_TOK - 1) k = L_TOK - 1;       // clamp: bias -1e30 masks these cols
    const int sj = (j >> 1) & 3;
    const bf16* src = base + (size_t)k * (3 * C_DIM) + C_DIM + h * HD + ((slot ^ sj) * 8);
    async_cp16(src, &kL[c * 512]);
  }

  // ---- V transpose writes (vmcnt wait covers only the V loads) ----
  {
    ushort ea0[8], ea1[8];
    *(uint4*)ea0 = a0; *(uint4*)ea1 = a1;
#pragma unroll
    for (int e = 0; e < 8; e++) {
      uint32_t pack = (uint32_t)ea0[e] | ((uint32_t)ea1[e] << 16);
      *(uint32_t*)&vT[(c8a + e) * VSTR + 2 * r0a] = pack;
    }
    if (h1) {
      ushort eb0[8], eb1[8];
      *(uint4*)eb0 = b0; *(uint4*)eb1 = b1;
#pragma unroll
      for (int e = 0; e < 8; e++) {
        uint32_t pack = (uint32_t)eb0[e] | ((uint32_t)eb1[e] << 16);
        *(uint32_t*)&vT[(c8b + e) * VSTR + 2 * r0b] = pack;
      }
    }
  }
  // zero V pad rows [196,224) (P there is exactly 0, but LDS garbage could be NaN)
  for (int idx = tid; idx < HD * 14; idx += 256) {
    int d = idx / 14, pr = idx - d * 14;
    *(uint32_t*)&vT[d * VSTR + L_TOK + 2 * pr] = 0;
  }
  __syncthreads();

  const bf16* biasB = biasb + (size_t)h * QP * KPAD;

#pragma unroll
  for (int ii = 0; ii < 4; ii++) {
    const int rg = wave + 4 * ii;
    if (rg < 13) {
      const int row0 = rg * 16;
      int qrow = row0 + colb; if (qrow > L_TOK - 1) qrow = L_TOK - 1;
      const frag8 aq = *(const frag8*)(base + (size_t)qrow * (3 * C_DIM) + h * HD + quad * 8);
      const bf16* bRow = biasB + (size_t)(row0 + colb) * KPAD;

      floatx4 o0 = (floatx4)(0.f), o1 = (floatx4)(0.f);
      float lsum = 0.f;
#pragma unroll
      for (int kk = 0; kk < 7; kk++) {
        const frag8 k0 = *(const frag8*)&kL[((2 * kk) * 16 + colb) * 32 + kswz];
        const frag8 k1 = *(const frag8*)&kL[((2 * kk + 1) * 16 + colb) * 32 + kswz];
        floatx4 s0 = __builtin_amdgcn_mfma_f32_16x16x32_bf16(k0, aq, (floatx4)(0.f), 0, 0, 0);
        floatx4 s1 = __builtin_amdgcn_mfma_f32_16x16x32_bf16(k1, aq, (floatx4)(0.f), 0, 0, 0);
        const frag8 bb = *(const frag8*)&bRow[kk * 32 + quad * 8];
        frag8 ap;
#pragma unroll
        for (int e = 0; e < 4; e++) {
          float p = EXP2(s0[e] + bfu2f(bb[e]));
          lsum += p;
          ap[e] = (short)f2bf_bits(p);
        }
#pragma unroll
        for (int e = 0; e < 4; e++) {
          float p = EXP2(s1[e] + bfu2f(bb[4 + e]));
          lsum += p;
          ap[4 + e] = (short)f2bf_bits(p);
        }
        const frag8 bv0 = *(const frag8*)&vT[colb * VSTR + kk * 32 + quad * 8];
        const frag8 bv1 = *(const frag8*)&vT[(16 + colb) * VSTR + kk * 32 + quad * 8];
        o0 = __builtin_amdgcn_mfma_f32_16x16x32_bf16(ap, bv0, o0, 0, 0, 0);
        o1 = __builtin_amdgcn_mfma_f32_16x16x32_bf16(ap, bv1, o1, 0, 0, 0);
      }
      lsum += __shfl_xor(lsum, 16, 64);
      lsum += __shfl_xor(lsum, 32, 64);
      const float rl = 1.0f / lsum;
#pragma unroll
      for (int r = 0; r < 4; r++) {
        const float rn = __shfl(rl, rsub + r, 64);
        const int grow = row0 + rsub + r;
        if (grow < L_TOK) {
          base[(size_t)grow * (3 * C_DIM) + h * HD + colb] = __float2bfloat16(o0[r] * rn);
          base[(size_t)grow * (3 * C_DIM) + h * HD + 16 + colb] = __float2bfloat16(o1[r] * rn);
        }
      }
    }
  }
}

extern "C" void kernel_launch(void* const* d_in, const int* in_sizes, int n_in,
                              void* d_out, int out_size, void* d_ws, size_t ws_size,
                              hipStream_t stream) {
  const float* x      = (const float*)d_in[0];
  const float* qkv_w  = (const float*)d_in[1];
  const float* qkv_b  = (const float*)d_in[2];
  const float* proj_w = (const float*)d_in[3];
  const float* proj_b = (const float*)d_in[4];
  const float* btab   = (const float*)d_in[5];
  const int*   relidx = (const int*)d_in[6];
  float* out = (float*)d_out;

  const size_t M = (size_t)B_WIN * L_TOK;  // 100352 = 392 * 256
  char* ws = (char*)d_ws;
  size_t off = 0;
  bf16*  qkv   = (bf16*)(ws + off);  off += M * 1152 * 2;              // 231.2 MB
  bf16*  wT1   = (bf16*)(ws + off);  off += (size_t)1152 * 384 * 2;    // 0.88 MB
  bf16*  wT2   = (bf16*)(ws + off);  off += (size_t)384 * 384 * 2;     // 0.29 MB
  bf16*  biasb = (bf16*)(ws + off);  off += (size_t)NH * QP * KPAD * 2;// 1.12 MB

  // x cast to bf16: prefer workspace; fall back to d_out aliasing.
  bf16* xb = (ws_size >= off + M * C_DIM * sizeof(bf16))
                 ? (bf16*)(ws + off) : (bf16*)d_out;

  cast_to_bf16<<<(int)(M * C_DIM / 4 / 256), 256, 0, stream>>>(x, xb);
  transpose_cast<<<(384 * 1152 + 255) / 256, 256, 0, stream>>>(qkv_w, wT1, 384, 1152);
  transpose_cast<<<(384 * 384 + 255) / 256, 256, 0, stream>>>(proj_w, wT2, 384, 384);
  bias_fill<<<(NH * QP * KPAD) / 256, 256, 0, stream>>>(btab, relidx, biasb);

  // 392 bm-tiles of 256 rows; panel=14 -> A super-panel 2.75 MB (XCD-L2 fit)
  gemm_bt<bf16, 384><<<392 * 9, 256, 0, stream>>>(xb, wT1, qkv_b, qkv,
                                                  (int)M, 1152, C_DIM, 9, 14);
  attn_win<<<dim3(B_WIN, NH), 256, 0, stream>>>(qkv, biasb);
  gemm_bt<float, 1152><<<392 * 3, 256, 0, stream>>>(qkv, wT2, proj_b, out,
                                                    (int)M, 384, 0, 3, 14);
}

// Round 13
// 611.527 us; speedup vs baseline: 1.1070x; 1.0286x over previous
//
#include <hip/hip_runtime.h>
#include <hip/hip_bf16.h>
#include <stdint.h>

typedef __hip_bfloat16 bf16;
typedef __attribute__((ext_vector_type(8))) short frag8;     // 8 bf16 = 4 VGPRs
typedef __attribute__((ext_vector_type(4))) float floatx4;   // MFMA acc

#define B_WIN 512
#define L_TOK 196
#define C_DIM 384
#define NH    12
#define HD    32
#define QP    208   // 13*16 q-rows padded
#define KPAD  224   // 14*16 k padded (exactly 56 P-vals/lane = 7 PV chunks)
#define VSTR  236   // vT row stride: 472B. write: 2-way; read: free
// scale = hd^-0.5 * log2(e)  (exp2 softmax; base change folded into logits+bias)
#define QSCALE 0.2550348555f

#if defined(__has_builtin)
#if __has_builtin(__builtin_amdgcn_exp2f)
#define EXP2(x) __builtin_amdgcn_exp2f(x)
#endif
#endif
#ifndef EXP2
#define EXP2(x) exp2f(x)
#endif

__device__ __forceinline__ void async_cp16(const void* g, void* l) {
  __builtin_amdgcn_global_load_lds(
      (const __attribute__((address_space(1))) unsigned int*)g,
      (__attribute__((address_space(3))) unsigned int*)l, 16, 0, 0);
}

__device__ __forceinline__ unsigned short f2bf_bits(float f) {
  bf16 b = __float2bfloat16(f);
  return *(unsigned short*)&b;
}

__device__ __forceinline__ float bfu2f(short u) {
  union { uint32_t i; float f; } c;
  c.i = ((uint32_t)(unsigned short)u) << 16;
  return c.f;
}

// ---------------- x cast: fp32 -> bf16, 4 elems/thread ----------------
__global__ void cast_to_bf16(const float* __restrict__ src, bf16* __restrict__ dst) {
  int i = blockIdx.x * 256 + threadIdx.x;   // grid sized exactly: n/4 threads
  float4 v = ((const float4*)src)[i];
  ushort4 o;
  o.x = f2bf_bits(v.x); o.y = f2bf_bits(v.y);
  o.z = f2bf_bits(v.z); o.w = f2bf_bits(v.w);
  ((ushort4*)dst)[i] = o;
}

// ---------------- weight transpose+cast: src[K][N] fp32 -> dst[N][K] bf16 ----
__global__ void transpose_cast(const float* __restrict__ src, bf16* __restrict__ dst,
                               int K, int N) {
  int idx = blockIdx.x * 256 + threadIdx.x;
  if (idx >= K * N) return;
  int k = idx / N, n = idx - k * N;
  dst[n * K + k] = __float2bfloat16(src[idx]);
}

// ------- bias precompute (bf16, per-kk contiguous): biasb[h][q 208][r2 224] ---
// r2 = kk*32 + quad*8 + i; maps to k = kk*32 + quad*8 + (i>=4?4:0) + (i&3)
// (the pi-permuted position matching the swapped-QK register layout, so each
//  lane reads ONE bf16x8 per kk). Pre-multiplied by log2(e).
// k >= 196: -1e30 (exp2 -> 0 masks those columns; K pad rows need no zeroing).
__global__ void bias_fill(const float* __restrict__ table, const int* __restrict__ rel,
                          bf16* __restrict__ biasb) {
  int idx = blockIdx.x * 256 + threadIdx.x;  // 12*208*224 = 559104 exact
  int h = idx / (QP * KPAD);
  int rem = idx - h * (QP * KPAD);
  int q = rem / KPAD, r2 = rem - q * KPAD;
  int kk = r2 >> 5, quad = (r2 >> 3) & 3, i = r2 & 7;
  int k = kk * 32 + quad * 8 + ((i >= 4) ? 4 : 0) + (i & 3);
  float v;
  if (q >= L_TOK)      v = 0.f;
  else if (k >= L_TOK) v = -1e30f;
  else                 v = table[rel[q * L_TOK + k] * NH + h] * 1.4426950408889634f;
  biasb[idx] = __float2bfloat16(v);
}

__device__ __forceinline__ void storev(bf16* p, float v)  { *p = __float2bfloat16(v); }
__device__ __forceinline__ void storev(float* p, float v) { *p = v; }

// ------- GEMM: C[M,N] = A[M,K](lda) @ Bt[N,K]^T + bias, C row-stride = N -------
// EXACT r5 structure (measured best: 156us, MfmaUtil 24%): 128x128 tile, both
// operands async-LDS-staged, 3-buffer, 2-ahead, counted vmcnt (never 0 in the
// steady loop; 4 stage ops/wave -> vmcnt(4) drains stage t+1, t+2 in flight).
// r9/r10 (direct-operand) and r12 (256x128 retile) all measured WORSE.
// NEW vs r5: bijective XCD swizzle (grid % 8 == 0 for both gemms). Default
// dispatch round-robins blocks over 8 XCDs -> each 4MB XCD-L2 sees slices of
// multiple 2.75MB A-panels (r12: FETCH 190MB vs 78 ideal). Swizzle gives each
// XCD a CONTIGUOUS logical range -> its own panel slice -> L2-fit.
template <typename OT>
__global__ __launch_bounds__(256) void gemm_bt(
    const bf16* __restrict__ A, const bf16* __restrict__ Bt,
    const float* __restrict__ bias, OT* __restrict__ C,
    int M, int N, int K, int lda, int qcols, int nbn, int panel) {
  __shared__ __align__(16) bf16 sA[3][128 * 32];
  __shared__ __align__(16) bf16 sB[3][128 * 32];
  const int tid = threadIdx.x;
  const int wave = tid >> 6, lane = tid & 63;
  // bijective XCD swizzle: block i runs on XCD i%8; give it logical id
  // (i%8)*q + i/8 so XCD x owns contiguous ids [x*q, (x+1)*q). Requires
  // gridDim.x % 8 == 0 (7056 and 2352 both are).
  const int nwg = gridDim.x;
  const int qx = nwg >> 3;
  const int bid = (blockIdx.x & 7) * qx + (blockIdx.x >> 3);
  const int SUPER = panel * nbn;
  const int sb = bid / SUPER, rsp = bid - sb * SUPER;
  const long bm = (long)(sb * panel + rsp % panel) * 128;
  const long bn = (long)(rsp / panel) * 128;

  const int srow = wave * 32 + (lane >> 2);
  const int scol = (lane & 3) * 8;
  const bf16* gA = A + (bm + srow) * (long)lda + scol;
  const bf16* gB = Bt + (bn + srow) * (long)K + scol;

  floatx4 acc[4][4];
#pragma unroll
  for (int i = 0; i < 4; i++)
#pragma unroll
    for (int j = 0; j < 4; j++) acc[i][j] = (floatx4)(0.f);

  const int wr = (wave & 1) * 64;
  const int wc = (wave >> 1) * 64;
  const int nst = K >> 5;   // k-steps of 32 (384 -> 12)

#define STAGE(s, buf)                                                        \
  do {                                                                       \
    _Pragma("unroll")                                                        \
    for (int j = 0; j < 2; j++) {                                            \
      async_cp16(gA + (size_t)j * 16 * lda + (s) * 32,                       \
                 &sA[buf][(wave * 32 + j * 16) * 32]);                       \
      async_cp16(gB + (size_t)j * 16 * K + (s) * 32,                         \
                 &sB[buf][(wave * 32 + j * 16) * 32]);                       \
    }                                                                        \
  } while (0)

  STAGE(0, 0);
  STAGE(1, 1);
  asm volatile("s_waitcnt vmcnt(4)" ::: "memory");   // stage 0 landed
  __builtin_amdgcn_s_barrier();

  int cur = 0;
  for (int t = 0; t < nst; ++t) {
    if (t + 2 < nst) {
      int nb = cur + 2; if (nb >= 3) nb -= 3;
      STAGE(t + 2, nb);
    }
    frag8 af[4], bfr[4];
#pragma unroll
    for (int mi = 0; mi < 4; mi++)
      af[mi] = *(const frag8*)&sA[cur][(wr + mi * 16 + (lane & 15)) * 32 + (lane >> 4) * 8];
#pragma unroll
    for (int ni = 0; ni < 4; ni++)
      bfr[ni] = *(const frag8*)&sB[cur][(wc + ni * 16 + (lane & 15)) * 32 + (lane >> 4) * 8];
#pragma unroll
    for (int mi = 0; mi < 4; mi++)
#pragma unroll
      for (int ni = 0; ni < 4; ni++)
        acc[mi][ni] = __builtin_amdgcn_mfma_f32_16x16x32_bf16(af[mi], bfr[ni], acc[mi][ni], 0, 0, 0);
    if (t + 1 < nst) {
      if (t + 2 < nst) asm volatile("s_waitcnt vmcnt(4)" ::: "memory"); // t+1 landed
      else             asm volatile("s_waitcnt vmcnt(0)" ::: "memory"); // tail drain
      __builtin_amdgcn_s_barrier();
    }
    cur = (cur == 2) ? 0 : cur + 1;
  }
#undef STAGE

#pragma unroll
  for (int ni = 0; ni < 4; ni++) {
    const long col = bn + wc + ni * 16 + (lane & 15);
    const float bv = bias[col];
#pragma unroll
    for (int mi = 0; mi < 4; mi++)
#pragma unroll
      for (int r = 0; r < 4; r++) {
        const long row = bm + wr + mi * 16 + (lane >> 4) * 4 + r;
        float val = acc[mi][ni][r] + bv;
        if (col < qcols) val *= QSCALE;
        storev(&C[row * N + col], val);
      }
  }
}

// ---------------- fused window attention (v7: v5/v6 hybrid, no forced cap) ---
// 256 threads / 4 waves, NO min-waves clause (r2/r4 lesson: forcing spills).
// Register diet instead: QK/PV interleaved per kk (transient ap, 4 VGPR),
// bf16 bias one frag8 per kk, Q loaded JIT per rg.
__global__ __launch_bounds__(256) void attn_win(
    bf16* __restrict__ qkv, const bf16* __restrict__ biasb) {
  __shared__ __align__(16) bf16 kL[KPAD * 32];     // 14336 B, linear 64B rows
  __shared__ __align__(16) bf16 vT[HD * VSTR];     // 15104 B  (total 29440 B)
  const int b = blockIdx.x, h = blockIdx.y;
  const int tid = threadIdx.x, wave = tid >> 6, lane = tid & 63;
  bf16* base = qkv + (size_t)b * L_TOK * (3 * C_DIM);

  const int colb = lane & 15;
  const int quad = lane >> 4;
  const int rsub = quad * 4;
  const int kswz = (quad ^ ((colb >> 1) & 3)) * 8;   // slot-XOR for kL reads

  // ---- V gather: issue ALL global loads first (oldest in vmem queue) ----
  const bf16* vbase = base + 2 * C_DIM + h * HD;
  const int r0a = tid >> 2, c8a = (tid & 3) * 8;
  const bf16* ga = vbase + (size_t)(2 * r0a) * (3 * C_DIM) + c8a;
  uint4 a0 = *(const uint4*)ga;
  uint4 a1 = *(const uint4*)(ga + 3 * C_DIM);
  const int i1 = tid + 256;
  const bool h1 = i1 < 392;
  const int r0b = h1 ? (i1 >> 2) : r0a, c8b = h1 ? (i1 & 3) * 8 : c8a;
  const bf16* gb = vbase + (size_t)(2 * r0b) * (3 * C_DIM) + c8b;
  uint4 b0 = make_uint4(0, 0, 0, 0), b1 = make_uint4(0, 0, 0, 0);
  if (h1) { b0 = *(const uint4*)gb; b1 = *(const uint4*)(gb + 3 * C_DIM); }

  // ---- K: async global->LDS, 14 chunks of 1024B (rows j = c*16..c*16+15).
  // LDS is linear; the slot permutation is applied on the global source:
  // LDS slot w of row j holds K[pi(j)] quad (w ^ ((j>>1)&3)).
  for (int c = wave; c < 14; c += 4) {
    const int j = c * 16 + (lane >> 2);
    const int slot = lane & 3;
    const int t = j >> 4, qd = (j >> 2) & 3, rr = j & 3;
    int k = (t >> 1) * 32 + qd * 8 + (t & 1) * 4 + rr;
    if (k > L_TOK - 1) k = L_TOK - 1;       // clamp: bias -1e30 masks these cols
    const int sj = (j >> 1) & 3;
    const bf16* src = base + (size_t)k * (3 * C_DIM) + C_DIM + h * HD + ((slot ^ sj) * 8);
    async_cp16(src, &kL[c * 512]);
  }

  // ---- V transpose writes (vmcnt wait covers only the V loads) ----
  {
    ushort ea0[8], ea1[8];
    *(uint4*)ea0 = a0; *(uint4*)ea1 = a1;
#pragma unroll
    for (int e = 0; e < 8; e++) {
      uint32_t pack = (uint32_t)ea0[e] | ((uint32_t)ea1[e] << 16);
      *(uint32_t*)&vT[(c8a + e) * VSTR + 2 * r0a] = pack;
    }
    if (h1) {
      ushort eb0[8], eb1[8];
      *(uint4*)eb0 = b0; *(uint4*)eb1 = b1;
#pragma unroll
      for (int e = 0; e < 8; e++) {
        uint32_t pack = (uint32_t)eb0[e] | ((uint32_t)eb1[e] << 16);
        *(uint32_t*)&vT[(c8b + e) * VSTR + 2 * r0b] = pack;
      }
    }
  }
  // zero V pad rows [196,224) (P there is exactly 0, but LDS garbage could be NaN)
  for (int idx = tid; idx < HD * 14; idx += 256) {
    int d = idx / 14, pr = idx - d * 14;
    *(uint32_t*)&vT[d * VSTR + L_TOK + 2 * pr] = 0;
  }
  __syncthreads();

  const bf16* biasB = biasb + (size_t)h * QP * KPAD;

#pragma unroll
  for (int ii = 0; ii < 4; ii++) {
    const int rg = wave + 4 * ii;
    if (rg < 13) {
      const int row0 = rg * 16;
      int qrow = row0 + colb; if (qrow > L_TOK - 1) qrow = L_TOK - 1;
      const frag8 aq = *(const frag8*)(base + (size_t)qrow * (3 * C_DIM) + h * HD + quad * 8);
      const bf16* bRow = biasB + (size_t)(row0 + colb) * KPAD;

      floatx4 o0 = (floatx4)(0.f), o1 = (floatx4)(0.f);
      float lsum = 0.f;
#pragma unroll
      for (int kk = 0; kk < 7; kk++) {
        const frag8 k0 = *(const frag8*)&kL[((2 * kk) * 16 + colb) * 32 + kswz];
        const frag8 k1 = *(const frag8*)&kL[((2 * kk + 1) * 16 + colb) * 32 + kswz];
        floatx4 s0 = __builtin_amdgcn_mfma_f32_16x16x32_bf16(k0, aq, (floatx4)(0.f), 0, 0, 0);
        floatx4 s1 = __builtin_amdgcn_mfma_f32_16x16x32_bf16(k1, aq, (floatx4)(0.f), 0, 0, 0);
        const frag8 bb = *(const frag8*)&bRow[kk * 32 + quad * 8];
        frag8 ap;
#pragma unroll
        for (int e = 0; e < 4; e++) {
          float p = EXP2(s0[e] + bfu2f(bb[e]));
          lsum += p;
          ap[e] = (short)f2bf_bits(p);
        }
#pragma unroll
        for (int e = 0; e < 4; e++) {
          float p = EXP2(s1[e] + bfu2f(bb[4 + e]));
          lsum += p;
          ap[4 + e] = (short)f2bf_bits(p);
        }
        const frag8 bv0 = *(const frag8*)&vT[colb * VSTR + kk * 32 + quad * 8];
        const frag8 bv1 = *(const frag8*)&vT[(16 + colb) * VSTR + kk * 32 + quad * 8];
        o0 = __builtin_amdgcn_mfma_f32_16x16x32_bf16(ap, bv0, o0, 0, 0, 0);
        o1 = __builtin_amdgcn_mfma_f32_16x16x32_bf16(ap, bv1, o1, 0, 0, 0);
      }
      lsum += __shfl_xor(lsum, 16, 64);
      lsum += __shfl_xor(lsum, 32, 64);
      const float rl = 1.0f / lsum;
#pragma unroll
      for (int r = 0; r < 4; r++) {
        const float rn = __shfl(rl, rsub + r, 64);
        const int grow = row0 + rsub + r;
        if (grow < L_TOK) {
          base[(size_t)grow * (3 * C_DIM) + h * HD + colb] = __float2bfloat16(o0[r] * rn);
          base[(size_t)grow * (3 * C_DIM) + h * HD + 16 + colb] = __float2bfloat16(o1[r] * rn);
        }
      }
    }
  }
}

extern "C" void kernel_launch(void* const* d_in, const int* in_sizes, int n_in,
                              void* d_out, int out_size, void* d_ws, size_t ws_size,
                              hipStream_t stream) {
  const float* x      = (const float*)d_in[0];
  const float* qkv_w  = (const float*)d_in[1];
  const float* qkv_b  = (const float*)d_in[2];
  const float* proj_w = (const float*)d_in[3];
  const float* proj_b = (const float*)d_in[4];
  const float* btab   = (const float*)d_in[5];
  const int*   relidx = (const int*)d_in[6];
  float* out = (float*)d_out;

  const size_t M = (size_t)B_WIN * L_TOK;  // 100352 = 784 * 128
  char* ws = (char*)d_ws;
  size_t off = 0;
  bf16*  qkv   = (bf16*)(ws + off);  off += M * 1152 * 2;              // 231.2 MB
  bf16*  wT1   = (bf16*)(ws + off);  off += (size_t)1152 * 384 * 2;    // 0.88 MB
  bf16*  wT2   = (bf16*)(ws + off);  off += (size_t)384 * 384 * 2;     // 0.29 MB
  bf16*  biasb = (bf16*)(ws + off);  off += (size_t)NH * QP * KPAD * 2;// 1.12 MB

  // x cast to bf16: prefer workspace; fall back to d_out aliasing.
  bf16* xb = (ws_size >= off + M * C_DIM * sizeof(bf16))
                 ? (bf16*)(ws + off) : (bf16*)d_out;

  cast_to_bf16<<<(int)(M * C_DIM / 4 / 256), 256, 0, stream>>>(x, xb);
  transpose_cast<<<(384 * 1152 + 255) / 256, 256, 0, stream>>>(qkv_w, wT1, 384, 1152);
  transpose_cast<<<(384 * 384 + 255) / 256, 256, 0, stream>>>(proj_w, wT2, 384, 384);
  bias_fill<<<(NH * QP * KPAD) / 256, 256, 0, stream>>>(btab, relidx, biasb);

  // 784 bm-tiles of 128 rows; panel=28 -> A panel 2.75MB; grids 7056/2352 % 8 == 0
  gemm_bt<bf16><<<784 * 9, 256, 0, stream>>>(xb, wT1, qkv_b, qkv,
                                             (int)M, 1152, 384, 384, C_DIM, 9, 28);
  attn_win<<<dim3(B_WIN, NH), 256, 0, stream>>>(qkv, biasb);
  gemm_bt<float><<<784 * 3, 256, 0, stream>>>(qkv, wT2, proj_b, out,
                                              (int)M, 384, 384, 1152, 0, 3, 28);
}

// Round 15
// 590.427 us; speedup vs baseline: 1.1466x; 1.0357x over previous
//
#include <hip/hip_runtime.h>
#include <hip/hip_bf16.h>
#include <stdint.h>

typedef __hip_bfloat16 bf16;
typedef __attribute__((ext_vector_type(8))) short frag8;     // 8 bf16 = 4 VGPRs
typedef __attribute__((ext_vector_type(4))) float floatx4;   // MFMA acc

#define B_WIN 512
#define L_TOK 196
#define C_DIM 384
#define NH    12
#define HD    32
#define QP    208   // 13*16 q-rows padded
#define KPAD  224   // 14*16 k padded (exactly 56 P-vals/lane = 7 PV chunks)
#define VSTR  236   // vT row stride: 472B. write: 2-way; read: free
// scale = hd^-0.5 * log2(e)  (exp2 softmax; base change folded into logits+bias)
#define QSCALE 0.2550348555f

// prep kernel block ranges (256 threads each)
#define NB_CAST 37632   // M*C_DIM/4/256 = 100352*384/4/256
#define NB_T1   1728    // 384*1152/256
#define NB_T2   576     // 384*384/256
#define NB_BIAS 2184    // 12*208*224/256

#if defined(__has_builtin)
#if __has_builtin(__builtin_amdgcn_exp2f)
#define EXP2(x) __builtin_amdgcn_exp2f(x)
#endif
#endif
#ifndef EXP2
#define EXP2(x) exp2f(x)
#endif

__device__ __forceinline__ void async_cp16(const void* g, void* l) {
  __builtin_amdgcn_global_load_lds(
      (const __attribute__((address_space(1))) unsigned int*)g,
      (__attribute__((address_space(3))) unsigned int*)l, 16, 0, 0);
}

__device__ __forceinline__ unsigned short f2bf_bits(float f) {
  bf16 b = __float2bfloat16(f);
  return *(unsigned short*)&b;
}

__device__ __forceinline__ float bfu2f(short u) {
  union { uint32_t i; float f; } c;
  c.i = ((uint32_t)(unsigned short)u) << 16;
  return c.f;
}

// ---------------- fused prep: cast + 2 transposes + bias fill ----------------
// Four independent elementwise tasks fused into one launch (saves 3 kernel
// boundaries ~15-20us each; r13 cross-round arithmetic shows ~150us of
// launch/gap overhead across 8 launches). Branches are block-uniform.
__global__ __launch_bounds__(256) void prep(
    const float* __restrict__ x, bf16* __restrict__ xb,
    const float* __restrict__ qkv_w, bf16* __restrict__ wT1,
    const float* __restrict__ proj_w, bf16* __restrict__ wT2,
    const float* __restrict__ table, const int* __restrict__ rel,
    bf16* __restrict__ biasb) {
  const int bid = blockIdx.x, tid = threadIdx.x;
  if (bid < NB_CAST) {
    // x cast fp32 -> bf16, 4 elems/thread, exact grid
    int i = bid * 256 + tid;
    float4 v = ((const float4*)x)[i];
    ushort4 o;
    o.x = f2bf_bits(v.x); o.y = f2bf_bits(v.y);
    o.z = f2bf_bits(v.z); o.w = f2bf_bits(v.w);
    ((ushort4*)xb)[i] = o;
  } else if (bid < NB_CAST + NB_T1) {
    // qkv_w transpose+cast: src[384][1152] -> dst[1152][384]
    int idx = (bid - NB_CAST) * 256 + tid;
    int k = idx / 1152, n = idx - k * 1152;
    wT1[n * 384 + k] = __float2bfloat16(qkv_w[idx]);
  } else if (bid < NB_CAST + NB_T1 + NB_T2) {
    // proj_w transpose+cast: src[384][384] -> dst[384][384]
    int idx = (bid - NB_CAST - NB_T1) * 256 + tid;
    int k = idx / 384, n = idx - k * 384;
    wT2[n * 384 + k] = __float2bfloat16(proj_w[idx]);
  } else {
    // bias precompute (bf16, per-kk contiguous): biasb[h][q 208][r2 224]
    // r2 = kk*32 + quad*8 + i -> k = kk*32 + quad*8 + (i>=4?4:0) + (i&3)
    // pre-multiplied by log2(e); k>=196 -> -1e30 (exp2 -> 0 masks those cols)
    int idx = (bid - NB_CAST - NB_T1 - NB_T2) * 256 + tid;  // < 559104 exact
    int h = idx / (QP * KPAD);
    int rem = idx - h * (QP * KPAD);
    int q = rem / KPAD, r2 = rem - q * KPAD;
    int kk = r2 >> 5, quad = (r2 >> 3) & 3, i = r2 & 7;
    int k = kk * 32 + quad * 8 + ((i >= 4) ? 4 : 0) + (i & 3);
    float v;
    if (q >= L_TOK)      v = 0.f;
    else if (k >= L_TOK) v = -1e30f;
    else                 v = table[rel[q * L_TOK + k] * NH + h] * 1.4426950408889634f;
    biasb[idx] = __float2bfloat16(v);
  }
}

__device__ __forceinline__ void storev(bf16* p, float v)  { *p = __float2bfloat16(v); }
__device__ __forceinline__ void storev(float* p, float v) { *p = v; }

// ------- GEMM: C[M,N] = A[M,K](lda) @ Bt[N,K]^T + bias, C row-stride = N -------
// EXACT r5 structure (measured best of 5 gemm variants: 156us, MfmaUtil 24%):
// 128x128 tile, both operands async-LDS-staged, 3-buffer, 2-ahead, counted
// vmcnt (4 stage ops/wave -> vmcnt(4) drains stage t+1, t+2 stays in flight;
// never 0 in the steady loop). r13's XCD swizzle REVERTED (measured: FETCH
// 100->134MB, dur 156->165 -- round-robin + L3 already handles panel reuse).
template <typename OT>
__global__ __launch_bounds__(256) void gemm_bt(
    const bf16* __restrict__ A, const bf16* __restrict__ Bt,
    const float* __restrict__ bias, OT* __restrict__ C,
    int M, int N, int K, int lda, int qcols, int nbn, int panel) {
  __shared__ __align__(16) bf16 sA[3][128 * 32];
  __shared__ __align__(16) bf16 sB[3][128 * 32];
  const int tid = threadIdx.x;
  const int wave = tid >> 6, lane = tid & 63;
  const int SUPER = panel * nbn;
  const int bid = blockIdx.x;
  const int sb = bid / SUPER, rsp = bid - sb * SUPER;
  const long bm = (long)(sb * panel + rsp % panel) * 128;
  const long bn = (long)(rsp / panel) * 128;

  const int srow = wave * 32 + (lane >> 2);
  const int scol = (lane & 3) * 8;
  const bf16* gA = A + (bm + srow) * (long)lda + scol;
  const bf16* gB = Bt + (bn + srow) * (long)K + scol;

  floatx4 acc[4][4];
#pragma unroll
  for (int i = 0; i < 4; i++)
#pragma unroll
    for (int j = 0; j < 4; j++) acc[i][j] = (floatx4)(0.f);

  const int wr = (wave & 1) * 64;
  const int wc = (wave >> 1) * 64;
  const int nst = K >> 5;   // k-steps of 32 (384 -> 12)

#define STAGE(s, buf)                                                        \
  do {                                                                       \
    _Pragma("unroll")                                                        \
    for (int j = 0; j < 2; j++) {                                            \
      async_cp16(gA + (size_t)j * 16 * lda + (s) * 32,                       \
                 &sA[buf][(wave * 32 + j * 16) * 32]);                       \
      async_cp16(gB + (size_t)j * 16 * K + (s) * 32,                         \
                 &sB[buf][(wave * 32 + j * 16) * 32]);                       \
    }                                                                        \
  } while (0)

  STAGE(0, 0);
  STAGE(1, 1);
  asm volatile("s_waitcnt vmcnt(4)" ::: "memory");   // stage 0 landed
  __builtin_amdgcn_s_barrier();

  int cur = 0;
  for (int t = 0; t < nst; ++t) {
    if (t + 2 < nst) {
      int nb = cur + 2; if (nb >= 3) nb -= 3;
      STAGE(t + 2, nb);
    }
    frag8 af[4], bfr[4];
#pragma unroll
    for (int mi = 0; mi < 4; mi++)
      af[mi] = *(const frag8*)&sA[cur][(wr + mi * 16 + (lane & 15)) * 32 + (lane >> 4) * 8];
#pragma unroll
    for (int ni = 0; ni < 4; ni++)
      bfr[ni] = *(const frag8*)&sB[cur][(wc + ni * 16 + (lane & 15)) * 32 + (lane >> 4) * 8];
#pragma unroll
    for (int mi = 0; mi < 4; mi++)
#pragma unroll
      for (int ni = 0; ni < 4; ni++)
        acc[mi][ni] = __builtin_amdgcn_mfma_f32_16x16x32_bf16(af[mi], bfr[ni], acc[mi][ni], 0, 0, 0);
    if (t + 1 < nst) {
      if (t + 2 < nst) asm volatile("s_waitcnt vmcnt(4)" ::: "memory"); // t+1 landed
      else             asm volatile("s_waitcnt vmcnt(0)" ::: "memory"); // tail drain
      __builtin_amdgcn_s_barrier();
    }
    cur = (cur == 2) ? 0 : cur + 1;
  }
#undef STAGE

#pragma unroll
  for (int ni = 0; ni < 4; ni++) {
    const long col = bn + wc + ni * 16 + (lane & 15);
    const float bv = bias[col];
#pragma unroll
    for (int mi = 0; mi < 4; mi++)
#pragma unroll
      for (int r = 0; r < 4; r++) {
        const long row = bm + wr + mi * 16 + (lane >> 4) * 4 + r;
        float val = acc[mi][ni][r] + bv;
        if (col < qcols) val *= QSCALE;
        storev(&C[row * N + col], val);
      }
  }
}

// ---------------- fused window attention (v7: v5/v6 hybrid, no forced cap) ---
// 256 threads / 4 waves, NO min-waves clause (r2/r4 lesson: forcing spills).
// Register diet instead: QK/PV interleaved per kk (transient ap, 4 VGPR),
// bf16 bias one frag8 per kk, Q loaded JIT per rg.
__global__ __launch_bounds__(256) void attn_win(
    bf16* __restrict__ qkv, const bf16* __restrict__ biasb) {
  __shared__ __align__(16) bf16 kL[KPAD * 32];     // 14336 B, linear 64B rows
  __shared__ __align__(16) bf16 vT[HD * VSTR];     // 15104 B  (total 29440 B)
  const int b = blockIdx.x, h = blockIdx.y;
  const int tid = threadIdx.x, wave = tid >> 6, lane = tid & 63;
  bf16* base = qkv + (size_t)b * L_TOK * (3 * C_DIM);

  const int colb = lane & 15;
  const int quad = lane >> 4;
  const int rsub = quad * 4;
  const int kswz = (quad ^ ((colb >> 1) & 3)) * 8;   // slot-XOR for kL reads

  // ---- V gather: issue ALL global loads first (oldest in vmem queue) ----
  const bf16* vbase = base + 2 * C_DIM + h * HD;
  const int r0a = tid >> 2, c8a = (tid & 3) * 8;
  const bf16* ga = vbase + (size_t)(2 * r0a) * (3 * C_DIM) + c8a;
  uint4 a0 = *(const uint4*)ga;
  uint4 a1 = *(const uint4*)(ga + 3 * C_DIM);
  const int i1 = tid + 256;
  const bool h1 = i1 < 392;
  const int r0b = h1 ? (i1 >> 2) : r0a, c8b = h1 ? (i1 & 3) * 8 : c8a;
  const bf16* gb = vbase + (size_t)(2 * r0b) * (3 * C_DIM) + c8b;
  uint4 b0 = make_uint4(0, 0, 0, 0), b1 = make_uint4(0, 0, 0, 0);
  if (h1) { b0 = *(const uint4*)gb; b1 = *(const uint4*)(gb + 3 * C_DIM); }

  // ---- K: async global->LDS, 14 chunks of 1024B (rows j = c*16..c*16+15).
  // LDS is linear; the slot permutation is applied on the global source:
  // LDS slot w of row j holds K[pi(j)] quad (w ^ ((j>>1)&3)).
  for (int c = wave; c < 14; c += 4) {
    const int j = c * 16 + (lane >> 2);
    const int slot = lane & 3;
    const int t = j >> 4, qd = (j >> 2) & 3, rr = j & 3;
    int k = (t >> 1) * 32 + qd * 8 + (t & 1) * 4 + rr;
    if (k > L_TOK - 1) k = L_TOK - 1;       // clamp: bias -1e30 masks these cols
    const int sj = (j >> 1) & 3;
    const bf16* src = base + (size_t)k * (3 * C_DIM) + C_DIM + h * HD + ((slot ^ sj) * 8);
    async_cp16(src, &kL[c * 512]);
  }

  // ---- V transpose writes (vmcnt wait covers only the V loads) ----
  {
    ushort ea0[8], ea1[8];
    *(uint4*)ea0 = a0; *(uint4*)ea1 = a1;
#pragma unroll
    for (int e = 0; e < 8; e++) {
      uint32_t pack = (uint32_t)ea0[e] | ((uint32_t)ea1[e] << 16);
      *(uint32_t*)&vT[(c8a + e) * VSTR + 2 * r0a] = pack;
    }
    if (h1) {
      ushort eb0[8], eb1[8];
      *(uint4*)eb0 = b0; *(uint4*)eb1 = b1;
#pragma unroll
      for (int e = 0; e < 8; e++) {
        uint32_t pack = (uint32_t)eb0[e] | ((uint32_t)eb1[e] << 16);
        *(uint32_t*)&vT[(c8b + e) * VSTR + 2 * r0b] = pack;
      }
    }
  }
  // zero V pad rows [196,224) (P there is exactly 0, but LDS garbage could be NaN)
  for (int idx = tid; idx < HD * 14; idx += 256) {
    int d = idx / 14, pr = idx - d * 14;
    *(uint32_t*)&vT[d * VSTR + L_TOK + 2 * pr] = 0;
  }
  __syncthreads();

  const bf16* biasB = biasb + (size_t)h * QP * KPAD;

#pragma unroll
  for (int ii = 0; ii < 4; ii++) {
    const int rg = wave + 4 * ii;
    if (rg < 13) {
      const int row0 = rg * 16;
      int qrow = row0 + colb; if (qrow > L_TOK - 1) qrow = L_TOK - 1;
      const frag8 aq = *(const frag8*)(base + (size_t)qrow * (3 * C_DIM) + h * HD + quad * 8);
      const bf16* bRow = biasB + (size_t)(row0 + colb) * KPAD;

      floatx4 o0 = (floatx4)(0.f), o1 = (floatx4)(0.f);
      float lsum = 0.f;
#pragma unroll
      for (int kk = 0; kk < 7; kk++) {
        const frag8 k0 = *(const frag8*)&kL[((2 * kk) * 16 + colb) * 32 + kswz];
        const frag8 k1 = *(const frag8*)&kL[((2 * kk + 1) * 16 + colb) * 32 + kswz];
        floatx4 s0 = __builtin_amdgcn_mfma_f32_16x16x32_bf16(k0, aq, (floatx4)(0.f), 0, 0, 0);
        floatx4 s1 = __builtin_amdgcn_mfma_f32_16x16x32_bf16(k1, aq, (floatx4)(0.f), 0, 0, 0);
        const frag8 bb = *(const frag8*)&bRow[kk * 32 + quad * 8];
        frag8 ap;
#pragma unroll
        for (int e = 0; e < 4; e++) {
          float p = EXP2(s0[e] + bfu2f(bb[e]));
          lsum += p;
          ap[e] = (short)f2bf_bits(p);
        }
#pragma unroll
        for (int e = 0; e < 4; e++) {
          float p = EXP2(s1[e] + bfu2f(bb[4 + e]));
          lsum += p;
          ap[4 + e] = (short)f2bf_bits(p);
        }
        const frag8 bv0 = *(const frag8*)&vT[colb * VSTR + kk * 32 + quad * 8];
        const frag8 bv1 = *(const frag8*)&vT[(16 + colb) * VSTR + kk * 32 + quad * 8];
        o0 = __builtin_amdgcn_mfma_f32_16x16x32_bf16(ap, bv0, o0, 0, 0, 0);
        o1 = __builtin_amdgcn_mfma_f32_16x16x32_bf16(ap, bv1, o1, 0, 0, 0);
      }
      lsum += __shfl_xor(lsum, 16, 64);
      lsum += __shfl_xor(lsum, 32, 64);
      const float rl = 1.0f / lsum;
#pragma unroll
      for (int r = 0; r < 4; r++) {
        const float rn = __shfl(rl, rsub + r, 64);
        const int grow = row0 + rsub + r;
        if (grow < L_TOK) {
          base[(size_t)grow * (3 * C_DIM) + h * HD + colb] = __float2bfloat16(o0[r] * rn);
          base[(size_t)grow * (3 * C_DIM) + h * HD + 16 + colb] = __float2bfloat16(o1[r] * rn);
        }
      }
    }
  }
}

extern "C" void kernel_launch(void* const* d_in, const int* in_sizes, int n_in,
                              void* d_out, int out_size, void* d_ws, size_t ws_size,
                              hipStream_t stream) {
  const float* x      = (const float*)d_in[0];
  const float* qkv_w  = (const float*)d_in[1];
  const float* qkv_b  = (const float*)d_in[2];
  const float* proj_w = (const float*)d_in[3];
  const float* proj_b = (const float*)d_in[4];
  const float* btab   = (const float*)d_in[5];
  const int*   relidx = (const int*)d_in[6];
  float* out = (float*)d_out;

  const size_t M = (size_t)B_WIN * L_TOK;  // 100352 = 784 * 128
  char* ws = (char*)d_ws;
  size_t off = 0;
  bf16*  qkv   = (bf16*)(ws + off);  off += M * 1152 * 2;              // 231.2 MB
  bf16*  wT1   = (bf16*)(ws + off);  off += (size_t)1152 * 384 * 2;    // 0.88 MB
  bf16*  wT2   = (bf16*)(ws + off);  off += (size_t)384 * 384 * 2;     // 0.29 MB
  bf16*  biasb = (bf16*)(ws + off);  off += (size_t)NH * QP * KPAD * 2;// 1.12 MB

  // x cast to bf16: prefer workspace; fall back to d_out aliasing.
  bf16* xb = (ws_size >= off + M * C_DIM * sizeof(bf16))
                 ? (bf16*)(ws + off) : (bf16*)d_out;

  prep<<<NB_CAST + NB_T1 + NB_T2 + NB_BIAS, 256, 0, stream>>>(
      x, xb, qkv_w, wT1, proj_w, wT2, btab, relidx, biasb);

  gemm_bt<bf16><<<784 * 9, 256, 0, stream>>>(xb, wT1, qkv_b, qkv,
                                             (int)M, 1152, 384, 384, C_DIM, 9, 28);
  attn_win<<<dim3(B_WIN, NH), 256, 0, stream>>>(qkv, biasb);
  gemm_bt<float><<<784 * 3, 256, 0, stream>>>(qkv, wT2, proj_b, out,
                                              (int)M, 384, 384, 1152, 0, 3, 28);
}